// Round 4
// baseline (14135.887 us; speedup 1.0000x reference)
//
#include <hip/hip_runtime.h>
#include <cstdint>

#define N_NODES 50000
#define N_EDGES 300000
#define N_REL 3
#define M_PAD  50048   // 391 * 128

typedef unsigned short ushort_t;
typedef __attribute__((ext_vector_type(8))) short short8;
typedef __attribute__((ext_vector_type(4))) float f32x4;

// ---------------------------------------------------------------------------
// fp32 -> bf16 hi/lo split (RNE)
// ---------------------------------------------------------------------------
__device__ __forceinline__ ushort_t f2bf(float x) {
    unsigned u = __float_as_uint(x);
    u += 0x7FFFu + ((u >> 16) & 1u);
    return (ushort_t)(u >> 16);
}
__device__ __forceinline__ float bf2f(ushort_t h) {
    return __uint_as_float(((unsigned)h) << 16);
}
__device__ __forceinline__ void split2(float x, ushort_t& h, ushort_t& l) {
    h = f2bf(x);
    l = f2bf(x - bf2f(h));
}

// ---------------------------------------------------------------------------
// Split-bf16 MFMA GEMM.
//  A: [M_PAD][K] bf16 row-major, hi+lo. B: [N][K] bf16 row-major (transposed
//  weights), hi+lo. C = [M_PAD][N] fp32 via Ahi*Bhi + Ahi*Blo + Alo*Bhi.
//  Tile 128x128, BK=32, 4 waves x (4x4 frags of mfma_f32_16x16x32_bf16).
//  LDS is in FRAGMENT ORDER (frag = 1024B, chunk l = (row=l&15, kgrp=l>>4)):
//  global_load_lds (wave-uniform dest, lane*16) stages it directly; compute
//  reads contiguous ds_read_b128 at lane*16 (conflict-free). k-slot mapping
//  identical for A and B (dot-product order invariance).
// ---------------------------------------------------------------------------
template<bool BIAS, bool RELU>
__global__ __launch_bounds__(256)
void gemm_bf16s(const ushort_t* __restrict__ Ahi, const ushort_t* __restrict__ Alo,
                const ushort_t* __restrict__ Bhi, const ushort_t* __restrict__ Blo,
                const float* __restrict__ bias, float* __restrict__ C,
                int K, int N)
{
    __shared__ __align__(16) ushort_t lds[16 * 512];   // 8 A-frags + 8 B-frags
    ushort_t* As = lds;
    ushort_t* Bs = lds + 8 * 512;

    const int tid  = threadIdx.x;
    const int wave = tid >> 6;
    const int lane = tid & 63;
    const int row0 = blockIdx.y * 128;
    const int col0 = blockIdx.x * 128;
    const int lr   = lane & 15;   // row (A) / col (B) within frag
    const int lk   = lane >> 4;   // k-group 0..3 (8 elems each)

    f32x4 acc[4][4];
#pragma unroll
    for (int m = 0; m < 4; ++m)
#pragma unroll
        for (int n = 0; n < 4; ++n) acc[m][n] = (f32x4)0.f;

    // staging: wave w loads A-frags {2w,2w+1} and B-frags {2w,2w+1}
    const int fa = 2 * wave;
    const size_t gA0 = (size_t)(row0 + 16 * fa      + lr) * K + lk * 8;
    const size_t gA1 = (size_t)(row0 + 16 * fa + 16 + lr) * K + lk * 8;
    const size_t gB0 = (size_t)(col0 + 16 * fa      + lr) * K + lk * 8;
    const size_t gB1 = (size_t)(col0 + 16 * fa + 16 + lr) * K + lk * 8;
    ushort_t* ldsA0 = As + fa * 512;          // wave-uniform dests
    ushort_t* ldsA1 = As + fa * 512 + 512;
    ushort_t* ldsB0 = Bs + fa * 512;
    ushort_t* ldsB1 = Bs + fa * 512 + 512;

    const int fmBase = (wave >> 1) * 4;   // this wave's compute frags
    const int fnBase = (wave & 1) * 4;
    const int KT = K >> 5;

    for (int p = 0; p < 3; ++p) {
        const ushort_t* Ap = (p < 2) ? Ahi : Alo;
        const ushort_t* Bp = (p == 1) ? Blo : Bhi;
        for (int kt = 0; kt < KT; ++kt) {
            const int k0 = kt << 5;
            __builtin_amdgcn_global_load_lds(
                (const __attribute__((address_space(1))) void*)(Ap + gA0 + k0),
                (__attribute__((address_space(3))) void*)ldsA0, 16, 0, 0);
            __builtin_amdgcn_global_load_lds(
                (const __attribute__((address_space(1))) void*)(Ap + gA1 + k0),
                (__attribute__((address_space(3))) void*)ldsA1, 16, 0, 0);
            __builtin_amdgcn_global_load_lds(
                (const __attribute__((address_space(1))) void*)(Bp + gB0 + k0),
                (__attribute__((address_space(3))) void*)ldsB0, 16, 0, 0);
            __builtin_amdgcn_global_load_lds(
                (const __attribute__((address_space(1))) void*)(Bp + gB1 + k0),
                (__attribute__((address_space(3))) void*)ldsB1, 16, 0, 0);
            __syncthreads();   // drains vmcnt -> staging visible

            short8 af[4], bfr[4];
#pragma unroll
            for (int m = 0; m < 4; ++m)
                af[m] = *(const short8*)(As + (fmBase + m) * 512 + lane * 8);
#pragma unroll
            for (int n = 0; n < 4; ++n)
                bfr[n] = *(const short8*)(Bs + (fnBase + n) * 512 + lane * 8);
#pragma unroll
            for (int m = 0; m < 4; ++m)
#pragma unroll
                for (int n = 0; n < 4; ++n)
                    acc[m][n] = __builtin_amdgcn_mfma_f32_16x16x32_bf16(
                        af[m], bfr[n], acc[m][n], 0, 0, 0);
            __syncthreads();   // all reads done before next stage overwrites
        }
    }

    // epilogue: C/D layout: col = lane&15, row = 4*(lane>>4) + j
    const int crBase = row0 + (wave >> 1) * 64 + lk * 4;
    const int ccBase = col0 + (wave & 1) * 64 + lr;
#pragma unroll
    for (int n = 0; n < 4; ++n) {
        const int c = ccBase + 16 * n;
        const float bv = BIAS ? bias[c] : 0.f;
#pragma unroll
        for (int m = 0; m < 4; ++m) {
            const int r = crBase + 16 * m;
            float* cp = C + (size_t)r * N + c;
#pragma unroll
            for (int j = 0; j < 4; ++j) {
                float v = acc[m][n][j] + bv;
                if (RELU) v = fmaxf(v, 0.f);
                cp[(size_t)j * N] = v;
            }
        }
    }
}

// ---------------------------------------------------------------------------
// Conversion kernels
// ---------------------------------------------------------------------------
// weights: W [K][N] f32 -> hi/lo [N][KP] bf16 (transposed, K zero-padded)
__global__ __launch_bounds__(256)
void wsplit_k(const float* __restrict__ W, ushort_t* __restrict__ hi,
              ushort_t* __restrict__ lo, int K, int N, int KP)
{
    long long idx = (long long)blockIdx.x * 256 + threadIdx.x;
    if (idx >= (long long)N * KP) return;
    const int k = (int)(idx % KP);
    const int n = (int)(idx / KP);
    float v = (k < K) ? W[(size_t)k * N + n] : 0.f;
    ushort_t h, l; split2(v, h, l);
    hi[idx] = h; lo[idx] = l;
}

// x [50000][782] f32 -> hi/lo [M_PAD][800] bf16 (row+col zero-padded)
__global__ __launch_bounds__(256)
void xsplit_k(const float* __restrict__ x, ushort_t* __restrict__ hi,
              ushort_t* __restrict__ lo)
{
    long long idx = (long long)blockIdx.x * 256 + threadIdx.x;
    if (idx >= (long long)M_PAD * 800) return;
    const int k = (int)(idx % 800);
    const int r = (int)(idx / 800);
    float v = (r < N_NODES && k < 782) ? x[(size_t)r * 782 + k] : 0.f;
    ushort_t h, l; split2(v, h, l);
    hi[idx] = h; lo[idx] = l;
}

// activations: A [M_PAD*d] f32 -> hi/lo bf16, optional fused relu
template<bool RELU>
__global__ __launch_bounds__(256)
void asplit_k(const float* __restrict__ A, ushort_t* __restrict__ hi,
              ushort_t* __restrict__ lo, long long n4)
{
    long long i = (long long)blockIdx.x * 256 + threadIdx.x;
    if (i >= n4) return;
    float4 v = reinterpret_cast<const float4*>(A)[i];
    if (RELU) {
        v.x = fmaxf(v.x, 0.f); v.y = fmaxf(v.y, 0.f);
        v.z = fmaxf(v.z, 0.f); v.w = fmaxf(v.w, 0.f);
    }
    ushort4 h, l;
    split2(v.x, h.x, l.x); split2(v.y, h.y, l.y);
    split2(v.z, h.z, l.z); split2(v.w, h.w, l.w);
    reinterpret_cast<ushort4*>(hi)[i] = h;
    reinterpret_cast<ushort4*>(lo)[i] = l;
}

// ---------------------------------------------------------------------------
// Graph helpers
// ---------------------------------------------------------------------------
__global__ __launch_bounds__(256)
void zero_kernel(float* __restrict__ p, int n)
{
    int i = blockIdx.x * 256 + threadIdx.x;
    if (i < n) p[i] = 0.f;
}

__global__ __launch_bounds__(256)
void count_kernel(const int* __restrict__ dst, const int* __restrict__ et,
                  float* __restrict__ cnt)
{
    int e = blockIdx.x * 256 + threadIdx.x;
    if (e < N_EDGES) atomicAdd(&cnt[(size_t)et[e] * N_NODES + dst[e]], 1.0f);
}

__global__ __launch_bounds__(256)
void scale_kernel(const int* __restrict__ dst, const int* __restrict__ et,
                  const float* __restrict__ cnt, float* __restrict__ scale)
{
    int e = blockIdx.x * 256 + threadIdx.x;
    if (e < N_EDGES)
        scale[e] = 1.0f / fmaxf(cnt[(size_t)et[e] * N_NODES + dst[e]], 1.0f);
}

// O[dst[e], j0 + c] += T[src[e], c] * scale[e]   for et[e]==rel.
// T is [M_PAD][4<<tshift] (col-block), O is [M_PAD][4<<oshift]; jo4 = j0/4.
__global__ __launch_bounds__(256)
void scatter_kernel(const int* __restrict__ src, const int* __restrict__ dst,
                    const int* __restrict__ et, const float* __restrict__ scale,
                    const float* __restrict__ T, float* __restrict__ O,
                    int rel, int tshift, int oshift, int jo4)
{
    const long long idx = (long long)blockIdx.x * 256 + threadIdx.x;
    const int e = (int)(idx >> tshift);
    if (e >= N_EDGES) return;
    if (et[e] != rel) return;
    const int d4 = (int)(idx & ((1 << tshift) - 1));
    const float s = scale[e];
    const float4 v = reinterpret_cast<const float4*>(T)[((size_t)src[e] << tshift) + d4];
    float* op = O + (((size_t)dst[e] << oshift) + jo4 + d4) * 4;
    atomicAdd(op + 0, v.x * s);
    atomicAdd(op + 1, v.y * s);
    atomicAdd(op + 2, v.z * s);
    atomicAdd(op + 3, v.w * s);
}

// final head: out[row] = A[row,0:256] @ W[256x3] + b; one wave per row
__global__ __launch_bounds__(64)
void head3_kernel(const float* __restrict__ A, const float* __restrict__ W,
                  const float* __restrict__ b, float* __restrict__ out)
{
    const int row  = blockIdx.x;
    const int lane = threadIdx.x;
    const float* a = A + (size_t)row * 256;
    float acc0 = 0.f, acc1 = 0.f, acc2 = 0.f;
#pragma unroll
    for (int c = 0; c < 4; ++c) {
        const int k = c * 64 + lane;
        const float av = a[k];
        const float* w = W + (size_t)k * 3;
        acc0 = fmaf(av, w[0], acc0);
        acc1 = fmaf(av, w[1], acc1);
        acc2 = fmaf(av, w[2], acc2);
    }
#pragma unroll
    for (int off = 32; off > 0; off >>= 1) {
        acc0 += __shfl_down(acc0, off);
        acc1 += __shfl_down(acc1, off);
        acc2 += __shfl_down(acc2, off);
    }
    if (lane == 0) {
        out[(size_t)row * 3 + 0] = acc0 + b[0];
        out[(size_t)row * 3 + 1] = acc1 + b[1];
        out[(size_t)row * 3 + 2] = acc2 + b[2];
    }
}

// ---------------------------------------------------------------------------
extern "C" void kernel_launch(void* const* d_in, const int* in_sizes, int n_in,
                              void* d_out, int out_size, void* d_ws, size_t ws_size,
                              hipStream_t stream)
{
    const float* x     = (const float*)d_in[0];
    const int*   ei    = (const int*)d_in[1];
    const int*   etype = (const int*)d_in[2];
    const float* w_in  = (const float*)d_in[3];
    const float* b_in  = (const float*)d_in[4];
    const float* w1    = (const float*)d_in[5];
    const float* root1 = (const float*)d_in[6];
    const float* b1    = (const float*)d_in[7];
    const float* w2    = (const float*)d_in[8];
    const float* root2 = (const float*)d_in[9];
    const float* b2    = (const float*)d_in[10];
    const float* w3    = (const float*)d_in[11];
    const float* root3 = (const float*)d_in[12];
    const float* b3    = (const float*)d_in[13];
    const float* w_o1  = (const float*)d_in[14];
    const float* b_o1  = (const float*)d_in[15];
    const float* w_o2  = (const float*)d_in[16];
    const float* b_o2  = (const float*)d_in[17];
    const float* w_o3  = (const float*)d_in[18];
    const float* b_o3  = (const float*)d_in[19];
    float* out = (float*)d_out;

    const int* src = ei;
    const int* dst = ei + N_EDGES;

    // ---- workspace carve-up (total ~445.6 MiB) ----
    float*    bufC   = (float*)d_ws;                             // M_PAD*1024 f32
    float*    bufT   = bufC + (size_t)M_PAD * 1024;              // M_PAD*256  f32
    ushort_t* a_hi   = (ushort_t*)(bufT + (size_t)M_PAD * 256);  // M_PAD*1024 bf16
    ushort_t* a_lo   = a_hi + (size_t)M_PAD * 1024;              // M_PAD*1024 bf16
    float*    cnt    = (float*)(a_lo + (size_t)M_PAD * 1024);    // 3*N_NODES
    float*    scale  = cnt + (size_t)N_REL * N_NODES;            // N_EDGES
    ushort_t* wscr_h = (ushort_t*)(scale + N_EDGES);             // 1024*1024 bf16
    ushort_t* wscr_l = wscr_h + (size_t)1024 * 1024;             // 1024*1024 bf16

    const dim3 blk(256);
    const int EB = (N_EDGES + 255) / 256;
    auto grid1 = [](long long n) { return dim3((unsigned)((n + 255) / 256)); };

    // ---- edge normalization (valid for all 3 layers) ----
    zero_kernel<<<grid1(N_REL * N_NODES), blk, 0, stream>>>(cnt, N_REL * N_NODES);
    count_kernel<<<EB, blk, 0, stream>>>(dst, etype, cnt);
    scale_kernel<<<EB, blk, 0, stream>>>(dst, etype, cnt, scale);

    // ---- input projection: h0 = relu(x @ w_in + b_in), K=800(pad), N=1024 ----
    xsplit_k<<<grid1((long long)M_PAD * 800), blk, 0, stream>>>(x, a_hi, a_lo);
    wsplit_k<<<grid1(1024LL * 800), blk, 0, stream>>>(w_in, wscr_h, wscr_l, 782, 1024, 800);
    gemm_bf16s<true, true><<<dim3(8, M_PAD / 128), blk, 0, stream>>>(
        a_hi, a_lo, wscr_h, wscr_l, b_in, bufC, 800, 1024);
    asplit_k<false><<<grid1((long long)M_PAD * 256), blk, 0, stream>>>(
        bufC, a_hi, a_lo, (long long)M_PAD * 256);

    // ---- RGCN layers ----
    const float* roots[3] = {root1, root2, root3};
    const float* ws_[3]   = {w1, w2, w3};
    const float* bs_[3]   = {b1, b2, b3};
    const int    Ks[3]    = {1024, 1024, 512};
    const int    Ds[3]    = {1024, 512, 256};
    const int    osh[3]   = {8, 7, 6};       // log2(D/4)

    for (int L = 0; L < 3; ++L) {
        const int K = Ks[L], D = Ds[L];
        // self: bufC = a @ root + b
        wsplit_k<<<grid1((long long)D * K), blk, 0, stream>>>(
            roots[L], wscr_h, wscr_l, K, D, K);
        gemm_bf16s<true, false><<<dim3(D / 128, M_PAD / 128), blk, 0, stream>>>(
            a_hi, a_lo, wscr_h, wscr_l, bs_[L], bufC, K, D);
        // relations, col-blocked by 256
        for (int r = 0; r < N_REL; ++r) {
            wsplit_k<<<grid1((long long)D * K), blk, 0, stream>>>(
                ws_[L] + (size_t)r * K * D, wscr_h, wscr_l, K, D, K);
            for (int jb = 0; jb < D / 256; ++jb) {
                gemm_bf16s<false, false><<<dim3(2, M_PAD / 128), blk, 0, stream>>>(
                    a_hi, a_lo, wscr_h + (size_t)jb * 256 * K,
                    wscr_l + (size_t)jb * 256 * K, nullptr, bufT, K, 256);
                scatter_kernel<<<(N_EDGES << 6) / 256, blk, 0, stream>>>(
                    src, dst, etype, scale, bufT, bufC, r, 6, osh[L], jb * 64);
            }
        }
        // relu + split into next activations
        asplit_k<true><<<grid1((long long)M_PAD * D / 4), blk, 0, stream>>>(
            bufC, a_hi, a_lo, (long long)M_PAD * D / 4);
    }

    // ---- MLP head ----
    wsplit_k<<<grid1(512LL * 256), blk, 0, stream>>>(w_o1, wscr_h, wscr_l, 256, 512, 256);
    gemm_bf16s<true, true><<<dim3(4, M_PAD / 128), blk, 0, stream>>>(
        a_hi, a_lo, wscr_h, wscr_l, b_o1, bufC, 256, 512);
    asplit_k<false><<<grid1((long long)M_PAD * 128), blk, 0, stream>>>(
        bufC, a_hi, a_lo, (long long)M_PAD * 128);
    wsplit_k<<<grid1(256LL * 512), blk, 0, stream>>>(w_o2, wscr_h, wscr_l, 512, 256, 512);
    gemm_bf16s<true, true><<<dim3(2, M_PAD / 128), blk, 0, stream>>>(
        a_hi, a_lo, wscr_h, wscr_l, b_o2, bufT, 512, 256);
    head3_kernel<<<N_NODES, dim3(64), 0, stream>>>(bufT, w_o3, b_o3, out);
}

// Round 7
// 7553.536 us; speedup vs baseline: 1.8714x; 1.8714x over previous
//
#include <hip/hip_runtime.h>
#include <cstdint>

#define N_NODES 50000
#define N_EDGES 300000
#define N_REL 3
#define M_PAD  50048   // 391 * 128

typedef unsigned short ushort_t;
typedef __attribute__((ext_vector_type(8))) short short8;
typedef __attribute__((ext_vector_type(4))) float f32x4;

// ---------------------------------------------------------------------------
// fp32 -> bf16 hi/lo split (RNE)
// ---------------------------------------------------------------------------
__device__ __forceinline__ ushort_t f2bf(float x) {
    unsigned u = __float_as_uint(x);
    u += 0x7FFFu + ((u >> 16) & 1u);
    return (ushort_t)(u >> 16);
}
__device__ __forceinline__ float bf2f(ushort_t h) {
    return __uint_as_float(((unsigned)h) << 16);
}
__device__ __forceinline__ void split2(float x, ushort_t& h, ushort_t& l) {
    h = f2bf(x);
    l = f2bf(x - bf2f(h));
}

// ---------------------------------------------------------------------------
// Split-bf16 MFMA GEMM (round-4 structure + bijective XCD-chunk swizzle).
//  A: [M_PAD][K] bf16 hi+lo. B: [N][K] bf16 (transposed weights) hi+lo.
//  C = [M_PAD][N] f32 via Ahi*Bhi + Ahi*Blo + Alo*Bhi.
//  Tile 128x128, BK=32, 4 waves x 4x4 frags of mfma_f32_16x16x32_bf16.
//  LDS in fragment order; global_load_lds width-16 stages it directly.
// ---------------------------------------------------------------------------
template<bool BIAS, bool RELU>
__global__ __launch_bounds__(256)
void gemm_bf16s(const ushort_t* __restrict__ Ahi, const ushort_t* __restrict__ Alo,
                const ushort_t* __restrict__ Bhi, const ushort_t* __restrict__ Blo,
                const float* __restrict__ bias, float* __restrict__ C,
                int K, int N)
{
    __shared__ __align__(16) ushort_t lds[16 * 512];   // 8 A-frags + 8 B-frags
    ushort_t* As = lds;
    ushort_t* Bs = lds + 8 * 512;

    // --- XCD-chunk swizzle (bijective, m204): XCD k gets a contiguous chunk
    // of linear block ids -> same-row col-tiles co-resident on one XCD L2.
    const int nwg = (int)(gridDim.x * gridDim.y);
    const int bid = (int)(blockIdx.y * gridDim.x + blockIdx.x);
    const int q = nwg >> 3, rm = nwg & 7;
    const int xcd = bid & 7, idx = bid >> 3;
    const int nbid = (xcd < rm ? xcd * (q + 1) : rm * (q + 1) + (xcd - rm) * q) + idx;
    const int bx = nbid % (int)gridDim.x;
    const int by = nbid / (int)gridDim.x;

    const int tid  = threadIdx.x;
    const int wave = tid >> 6;
    const int lane = tid & 63;
    const int row0 = by * 128;
    const int col0 = bx * 128;
    const int lr   = lane & 15;   // row (A) / col (B) within frag
    const int lk   = lane >> 4;   // k-group 0..3 (8 elems each)

    f32x4 acc[4][4];
#pragma unroll
    for (int m = 0; m < 4; ++m)
#pragma unroll
        for (int n = 0; n < 4; ++n) acc[m][n] = (f32x4)0.f;

    // staging: wave w loads A-frags {2w,2w+1} and B-frags {2w,2w+1}
    const int fa = 2 * wave;
    const size_t gA0 = (size_t)(row0 + 16 * fa      + lr) * K + lk * 8;
    const size_t gA1 = (size_t)(row0 + 16 * fa + 16 + lr) * K + lk * 8;
    const size_t gB0 = (size_t)(col0 + 16 * fa      + lr) * K + lk * 8;
    const size_t gB1 = (size_t)(col0 + 16 * fa + 16 + lr) * K + lk * 8;
    ushort_t* ldsA0 = As + fa * 512;          // wave-uniform dests
    ushort_t* ldsA1 = As + fa * 512 + 512;
    ushort_t* ldsB0 = Bs + fa * 512;
    ushort_t* ldsB1 = Bs + fa * 512 + 512;

    const int fmBase = (wave >> 1) * 4;   // this wave's compute frags
    const int fnBase = (wave & 1) * 4;
    const int KT = K >> 5;

    for (int p = 0; p < 3; ++p) {
        const ushort_t* Ap = (p < 2) ? Ahi : Alo;
        const ushort_t* Bp = (p == 1) ? Blo : Bhi;
        for (int kt = 0; kt < KT; ++kt) {
            const int k0 = kt << 5;
            __builtin_amdgcn_global_load_lds(
                (const __attribute__((address_space(1))) void*)(Ap + gA0 + k0),
                (__attribute__((address_space(3))) void*)ldsA0, 16, 0, 0);
            __builtin_amdgcn_global_load_lds(
                (const __attribute__((address_space(1))) void*)(Ap + gA1 + k0),
                (__attribute__((address_space(3))) void*)ldsA1, 16, 0, 0);
            __builtin_amdgcn_global_load_lds(
                (const __attribute__((address_space(1))) void*)(Bp + gB0 + k0),
                (__attribute__((address_space(3))) void*)ldsB0, 16, 0, 0);
            __builtin_amdgcn_global_load_lds(
                (const __attribute__((address_space(1))) void*)(Bp + gB1 + k0),
                (__attribute__((address_space(3))) void*)ldsB1, 16, 0, 0);
            __syncthreads();   // drains vmcnt -> staging visible

            short8 af[4], bfr[4];
#pragma unroll
            for (int m = 0; m < 4; ++m)
                af[m] = *(const short8*)(As + (fmBase + m) * 512 + lane * 8);
#pragma unroll
            for (int n = 0; n < 4; ++n)
                bfr[n] = *(const short8*)(Bs + (fnBase + n) * 512 + lane * 8);
#pragma unroll
            for (int m = 0; m < 4; ++m)
#pragma unroll
                for (int n = 0; n < 4; ++n)
                    acc[m][n] = __builtin_amdgcn_mfma_f32_16x16x32_bf16(
                        af[m], bfr[n], acc[m][n], 0, 0, 0);
            __syncthreads();   // all reads done before next stage overwrites
        }
    }

    // epilogue: C/D layout: col = lane&15, row = 4*(lane>>4) + j
    const int crBase = row0 + (wave >> 1) * 64 + lk * 4;
    const int ccBase = col0 + (wave & 1) * 64 + lr;
#pragma unroll
    for (int n = 0; n < 4; ++n) {
        const int c = ccBase + 16 * n;
        const float bv = BIAS ? bias[c] : 0.f;
#pragma unroll
        for (int m = 0; m < 4; ++m) {
            const int r = crBase + 16 * m;
            float* cp = C + (size_t)r * N + c;
#pragma unroll
            for (int j = 0; j < 4; ++j) {
                float v = acc[m][n][j] + bv;
                if (RELU) v = fmaxf(v, 0.f);
                cp[(size_t)j * N] = v;
            }
        }
    }
}

// ---------------------------------------------------------------------------
// Conversion kernels
// ---------------------------------------------------------------------------
// weights: W [K][N] f32 -> hi/lo [N][KP] bf16 (transposed, K zero-padded)
__global__ __launch_bounds__(256)
void wsplit_k(const float* __restrict__ W, ushort_t* __restrict__ hi,
              ushort_t* __restrict__ lo, int K, int N, int KP)
{
    long long idx = (long long)blockIdx.x * 256 + threadIdx.x;
    if (idx >= (long long)N * KP) return;
    const int k = (int)(idx % KP);
    const int n = (int)(idx / KP);
    float v = (k < K) ? W[(size_t)k * N + n] : 0.f;
    ushort_t h, l; split2(v, h, l);
    hi[idx] = h; lo[idx] = l;
}

// x [50000][782] f32 -> hi/lo [M_PAD][800] bf16 (row+col zero-padded)
__global__ __launch_bounds__(256)
void xsplit_k(const float* __restrict__ x, ushort_t* __restrict__ hi,
              ushort_t* __restrict__ lo)
{
    long long idx = (long long)blockIdx.x * 256 + threadIdx.x;
    if (idx >= (long long)M_PAD * 800) return;
    const int k = (int)(idx % 800);
    const int r = (int)(idx / 800);
    float v = (r < N_NODES && k < 782) ? x[(size_t)r * 782 + k] : 0.f;
    ushort_t h, l; split2(v, h, l);
    hi[idx] = h; lo[idx] = l;
}

// activations: A [M_PAD*d] f32 -> hi/lo bf16, optional fused relu
template<bool RELU>
__global__ __launch_bounds__(256)
void asplit_k(const float* __restrict__ A, ushort_t* __restrict__ hi,
              ushort_t* __restrict__ lo, long long n4)
{
    long long i = (long long)blockIdx.x * 256 + threadIdx.x;
    if (i >= n4) return;
    float4 v = reinterpret_cast<const float4*>(A)[i];
    if (RELU) {
        v.x = fmaxf(v.x, 0.f); v.y = fmaxf(v.y, 0.f);
        v.z = fmaxf(v.z, 0.f); v.w = fmaxf(v.w, 0.f);
    }
    ushort4 h, l;
    split2(v.x, h.x, l.x); split2(v.y, h.y, l.y);
    split2(v.z, h.z, l.z); split2(v.w, h.w, l.w);
    reinterpret_cast<ushort4*>(hi)[i] = h;
    reinterpret_cast<ushort4*>(lo)[i] = l;
}

// ---------------------------------------------------------------------------
// CSR build: count -> exclusive scan (3 kernels) -> fill
// key = rel * N_NODES + dst
// ---------------------------------------------------------------------------
__global__ __launch_bounds__(256)
void zero_kernel(int* __restrict__ p, int n)
{
    int i = blockIdx.x * 256 + threadIdx.x;
    if (i < n) p[i] = 0;
}

__global__ __launch_bounds__(256)
void counti_k(const int* __restrict__ dst, const int* __restrict__ et,
              int* __restrict__ cnt)
{
    int e = blockIdx.x * 256 + threadIdx.x;
    if (e < N_EDGES) atomicAdd(&cnt[et[e] * N_NODES + dst[e]], 1);
}

__global__ __launch_bounds__(256)
void scan1_k(const int* __restrict__ in, int* __restrict__ out,
             int* __restrict__ bsum, int n)
{
    __shared__ int s[256];
    int i = blockIdx.x * 256 + threadIdx.x;
    int v = (i < n) ? in[i] : 0;
    s[threadIdx.x] = v;
    __syncthreads();
    for (int d = 1; d < 256; d <<= 1) {
        int t = (threadIdx.x >= d) ? s[threadIdx.x - d] : 0;
        __syncthreads();
        s[threadIdx.x] += t;
        __syncthreads();
    }
    if (i < n) out[i] = s[threadIdx.x] - v;        // exclusive
    if (threadIdx.x == 255) bsum[blockIdx.x] = s[255];
}

__global__ __launch_bounds__(1024)
void scan2_k(int* __restrict__ bsum, int nb)       // exclusive, nb <= 1024
{
    __shared__ int s[1024];
    int v = ((int)threadIdx.x < nb) ? bsum[threadIdx.x] : 0;
    s[threadIdx.x] = v;
    __syncthreads();
    for (int d = 1; d < 1024; d <<= 1) {
        int t = (threadIdx.x >= d) ? s[threadIdx.x - d] : 0;
        __syncthreads();
        s[threadIdx.x] += t;
        __syncthreads();
    }
    if ((int)threadIdx.x < nb) bsum[threadIdx.x] = s[threadIdx.x] - v;
}

__global__ __launch_bounds__(256)
void scan3_k(int* __restrict__ out, const int* __restrict__ bsum, int n)
{
    int i = blockIdx.x * 256 + threadIdx.x;
    if (i < n) out[i] += bsum[blockIdx.x];
    if (i == 0) out[n] = N_EDGES;                  // sentinel: total
}

__global__ __launch_bounds__(256)
void fill_k(const int* __restrict__ src, const int* __restrict__ dst,
            const int* __restrict__ et, const int* __restrict__ offs,
            int* __restrict__ cursor, int* __restrict__ eidx)
{
    int e = blockIdx.x * 256 + threadIdx.x;
    if (e >= N_EDGES) return;
    int key = et[e] * N_NODES + dst[e];
    int p = atomicAdd(&cursor[key], 1);
    eidx[offs[key] + p] = src[e];                  // store src node id directly
}

// ---------------------------------------------------------------------------
// Pull aggregation: one wave per dst node (4 waves/block).
//  O[node, jo + c] += (1/cnt) * sum_{s in N_r(node)} T[s, c],  c in [0,256)
//  T: [M_PAD][256] f32 (col-block), coalesced 1KB row reads; non-atomic RMW.
// ---------------------------------------------------------------------------
__global__ __launch_bounds__(256)
void agg_pull(const int* __restrict__ eidx, const int* __restrict__ offs,
              const float* __restrict__ T, float* __restrict__ O,
              int Dout, int jo)
{
    const int node = blockIdx.x * 4 + (threadIdx.x >> 6);
    if (node >= N_NODES) return;
    const int lane = threadIdx.x & 63;
    const int beg = offs[node], end = offs[node + 1];
    if (beg == end) return;
    float4 acc = make_float4(0.f, 0.f, 0.f, 0.f);
    for (int t = beg; t < end; ++t) {
        const int s = eidx[t];
        const float4 v = reinterpret_cast<const float4*>(T + (size_t)s * 256)[lane];
        acc.x += v.x; acc.y += v.y; acc.z += v.z; acc.w += v.w;
    }
    const float inv = 1.0f / (float)(end - beg);
    float4* op = reinterpret_cast<float4*>(O + (size_t)node * Dout + jo) + lane;
    float4 cur = *op;
    cur.x += acc.x * inv; cur.y += acc.y * inv;
    cur.z += acc.z * inv; cur.w += acc.w * inv;
    *op = cur;
}

// final head: out[row] = A[row,0:256] @ W[256x3] + b; one wave per row
__global__ __launch_bounds__(64)
void head3_kernel(const float* __restrict__ A, const float* __restrict__ W,
                  const float* __restrict__ b, float* __restrict__ out)
{
    const int row  = blockIdx.x;
    const int lane = threadIdx.x;
    const float* a = A + (size_t)row * 256;
    float acc0 = 0.f, acc1 = 0.f, acc2 = 0.f;
#pragma unroll
    for (int c = 0; c < 4; ++c) {
        const int k = c * 64 + lane;
        const float av = a[k];
        const float* w = W + (size_t)k * 3;
        acc0 = fmaf(av, w[0], acc0);
        acc1 = fmaf(av, w[1], acc1);
        acc2 = fmaf(av, w[2], acc2);
    }
#pragma unroll
    for (int off = 32; off > 0; off >>= 1) {
        acc0 += __shfl_down(acc0, off);
        acc1 += __shfl_down(acc1, off);
        acc2 += __shfl_down(acc2, off);
    }
    if (lane == 0) {
        out[(size_t)row * 3 + 0] = acc0 + b[0];
        out[(size_t)row * 3 + 1] = acc1 + b[1];
        out[(size_t)row * 3 + 2] = acc2 + b[2];
    }
}

// ---------------------------------------------------------------------------
extern "C" void kernel_launch(void* const* d_in, const int* in_sizes, int n_in,
                              void* d_out, int out_size, void* d_ws, size_t ws_size,
                              hipStream_t stream)
{
    const float* x     = (const float*)d_in[0];
    const int*   ei    = (const int*)d_in[1];
    const int*   etype = (const int*)d_in[2];
    const float* w_in  = (const float*)d_in[3];
    const float* b_in  = (const float*)d_in[4];
    const float* w1    = (const float*)d_in[5];
    const float* root1 = (const float*)d_in[6];
    const float* b1    = (const float*)d_in[7];
    const float* w2    = (const float*)d_in[8];
    const float* root2 = (const float*)d_in[9];
    const float* b2    = (const float*)d_in[10];
    const float* w3    = (const float*)d_in[11];
    const float* root3 = (const float*)d_in[12];
    const float* b3    = (const float*)d_in[13];
    const float* w_o1  = (const float*)d_in[14];
    const float* b_o1  = (const float*)d_in[15];
    const float* w_o2  = (const float*)d_in[16];
    const float* b_o2  = (const float*)d_in[17];
    const float* w_o3  = (const float*)d_in[18];
    const float* b_o3  = (const float*)d_in[19];
    float* out = (float*)d_out;

    const int* src = ei;
    const int* dst = ei + N_EDGES;

    // ---- workspace carve-up (~468 MiB) ----
    float*    bufC   = (float*)d_ws;                             // M_PAD*1024 f32
    float*    bufT   = bufC + (size_t)M_PAD * 1024;              // M_PAD*256  f32
    ushort_t* a_hi   = (ushort_t*)(bufT + (size_t)M_PAD * 256);  // M_PAD*1024 bf16
    ushort_t* a_lo   = a_hi + (size_t)M_PAD * 1024;              // M_PAD*1024 bf16
    ushort_t* wscr_h = a_lo + (size_t)M_PAD * 1024;              // 1024*1024 bf16
    ushort_t* wscr_l = wscr_h + (size_t)1024 * 1024;             // 1024*1024 bf16
    int*      cnt_i  = (int*)(wscr_l + (size_t)1024 * 1024);     // 150000 (+cursor contiguous)
    int*      cursor = cnt_i + N_REL * N_NODES;                  // 150000
    int*      offs   = cursor + N_REL * N_NODES;                 // 150001
    int*      bsum   = offs + N_REL * N_NODES + 1;               // 1024
    int*      eidx   = bsum + 1024;                              // 300000

    const dim3 blk(256);
    const int EB = (N_EDGES + 255) / 256;
    const int NK = N_REL * N_NODES;                 // 150000
    const int SB = (NK + 255) / 256;                // 586 scan blocks
    auto grid1 = [](long long n) { return dim3((unsigned)((n + 255) / 256)); };

    // ---- CSR build (valid for all 3 layers) ----
    zero_kernel<<<grid1(2 * NK), blk, 0, stream>>>(cnt_i, 2 * NK);  // cnt + cursor
    counti_k<<<EB, blk, 0, stream>>>(dst, etype, cnt_i);
    scan1_k<<<SB, blk, 0, stream>>>(cnt_i, offs, bsum, NK);
    scan2_k<<<1, dim3(1024), 0, stream>>>(bsum, SB);
    scan3_k<<<SB, blk, 0, stream>>>(offs, bsum, NK);
    fill_k<<<EB, blk, 0, stream>>>(src, dst, etype, offs, cursor, eidx);

    // ---- input projection: h0 = relu(x @ w_in + b_in), K=800(pad), N=1024 ----
    xsplit_k<<<grid1((long long)M_PAD * 800), blk, 0, stream>>>(x, a_hi, a_lo);
    wsplit_k<<<grid1(1024LL * 800), blk, 0, stream>>>(w_in, wscr_h, wscr_l, 782, 1024, 800);
    gemm_bf16s<true, true><<<dim3(8, M_PAD / 128), blk, 0, stream>>>(
        a_hi, a_lo, wscr_h, wscr_l, b_in, bufC, 800, 1024);
    asplit_k<false><<<grid1((long long)M_PAD * 256), blk, 0, stream>>>(
        bufC, a_hi, a_lo, (long long)M_PAD * 256);

    // ---- RGCN layers ----
    const float* roots[3] = {root1, root2, root3};
    const float* ws_[3]   = {w1, w2, w3};
    const float* bs_[3]   = {b1, b2, b3};
    const int    Ks[3]    = {1024, 1024, 512};
    const int    Ds[3]    = {1024, 512, 256};
    const int    AGB      = (N_NODES + 3) / 4;     // agg blocks (4 nodes each)

    for (int L = 0; L < 3; ++L) {
        const int K = Ks[L], D = Ds[L];
        // self: bufC = a @ root + b
        wsplit_k<<<grid1((long long)D * K), blk, 0, stream>>>(
            roots[L], wscr_h, wscr_l, K, D, K);
        gemm_bf16s<true, false><<<dim3(D / 128, M_PAD / 128), blk, 0, stream>>>(
            a_hi, a_lo, wscr_h, wscr_l, bs_[L], bufC, K, D);
        // relations: transform col-block (256) then pull-aggregate into bufC
        for (int r = 0; r < N_REL; ++r) {
            wsplit_k<<<grid1((long long)D * K), blk, 0, stream>>>(
                ws_[L] + (size_t)r * K * D, wscr_h, wscr_l, K, D, K);
            for (int jb = 0; jb < D / 256; ++jb) {
                gemm_bf16s<false, false><<<dim3(2, M_PAD / 128), blk, 0, stream>>>(
                    a_hi, a_lo, wscr_h + (size_t)jb * 256 * K,
                    wscr_l + (size_t)jb * 256 * K, nullptr, bufT, K, 256);
                agg_pull<<<AGB, blk, 0, stream>>>(
                    eidx, offs + r * N_NODES, bufT, bufC, D, jb * 256);
            }
        }
        // relu + split into next activations
        asplit_k<true><<<grid1((long long)M_PAD * D / 4), blk, 0, stream>>>(
            bufC, a_hi, a_lo, (long long)M_PAD * D / 4);
    }

    // ---- MLP head ----
    wsplit_k<<<grid1(512LL * 256), blk, 0, stream>>>(w_o1, wscr_h, wscr_l, 256, 512, 256);
    gemm_bf16s<true, true><<<dim3(4, M_PAD / 128), blk, 0, stream>>>(
        a_hi, a_lo, wscr_h, wscr_l, b_o1, bufC, 256, 512);
    asplit_k<false><<<grid1((long long)M_PAD * 128), blk, 0, stream>>>(
        bufC, a_hi, a_lo, (long long)M_PAD * 128);
    wsplit_k<<<grid1(256LL * 512), blk, 0, stream>>>(w_o2, wscr_h, wscr_l, 512, 256, 512);
    gemm_bf16s<true, true><<<dim3(2, M_PAD / 128), blk, 0, stream>>>(
        a_hi, a_lo, wscr_h, wscr_l, b_o2, bufT, 512, 256);
    head3_kernel<<<N_NODES, dim3(64), 0, stream>>>(bufT, w_o3, b_o3, out);
}